// Round 4
// baseline (298.564 us; speedup 1.0000x reference)
//
#include <hip/hip_runtime.h>

// QLoRA NF4 forward: out[b,s,o] = 4.0 * sum_r (sum_i x[b,s,i]*W_A[r,i]) * W_B[o,r]
// B=4 S=2048 IN=4096 OUT=4096 R=8. All fp32.
// R4: fused kernel (overlap x-read and out-write streams across blocks)
//     = R1's proven no-spill phase 1 + R3's transposed-wBt coalesced phase 2.
//  - dequant writes wA [8][4096] and wBt [8][4096] (transposed B factor).
//  - fused: block = 8 rows; phase 1 wave-per-2-rows dot products -> LDS
//    interm[8][8]; phase 2 coalesced wBt loads + contiguous float4 stores.

static __device__ __constant__ float NF4_TBL[16] = {
    -1.0f, -0.6961928009986877f, -0.5250730514526367f, -0.39491748809814453f,
    -0.28444138169288635f, -0.18477343022823334f, -0.09105003625154495f, 0.0f,
    0.07958029955625534f, 0.16093020141124725f, 0.24611230194568634f,
    0.33791524171829224f, 0.44070982933044434f, 0.5626170039176941f,
    0.7229568362236328f, 1.0f};

__global__ void nf4_dequant_kernel(const int* __restrict__ codesA,
                                   const float* __restrict__ absA,
                                   const int* __restrict__ codesB,
                                   const float* __restrict__ absB,
                                   float* __restrict__ wA,    // [8][4096]
                                   float* __restrict__ wBt,   // [8][4096] transposed
                                   int n) {
    int id = blockIdx.x * blockDim.x + threadIdx.x;
    if (id < n) {
        wA[id] = NF4_TBL[codesA[id] & 15] * absA[id >> 6];
        // codes_B flat id = o*8 + r ; store transposed at [r][o]
        const int o = id >> 3;
        const int r = id & 7;
        wBt[r * 4096 + o] = NF4_TBL[codesB[id] & 15] * absB[id >> 6];
    }
}

__global__ __launch_bounds__(256, 4) void qlora_fused_kernel(
    const float* __restrict__ x,       // [8192][4096]
    const float* __restrict__ wA,      // [8][4096]
    const float* __restrict__ wBt,     // [8][4096]
    float* __restrict__ out) {         // [8192][4096]
    constexpr int IN4  = 4096 / 4;
    constexpr int ROWS = 8;

    __shared__ float4 interm4[ROWS][2];       // interm[8][8]

    const int t    = threadIdx.x;
    const int wave = t >> 6;
    const int lane = t & 63;
    const int row0 = blockIdx.x * ROWS;

    // ---- Phase 1: wave owns rows 2w, 2w+1 (R1 structure, 64 VGPR, no spill)
    {
        const int r0 = row0 + 2 * wave;
        const float4* __restrict__ x0  = (const float4*)(x + (size_t)r0 * 4096);
        const float4* __restrict__ x1  = (const float4*)(x + (size_t)(r0 + 1) * 4096);
        const float4* __restrict__ wA4 = (const float4*)wA;

        float acc0[8], acc1[8];
        #pragma unroll
        for (int r = 0; r < 8; ++r) { acc0[r] = 0.f; acc1[r] = 0.f; }

        #pragma unroll 4
        for (int c = 0; c < 16; ++c) {
            const int idx = lane + 64 * c;            // coalesced per wave
            const float4 xa = x0[idx];
            const float4 xb = x1[idx];
            #pragma unroll
            for (int r = 0; r < 8; ++r) {
                const float4 w = wA4[r * IN4 + idx];  // L2-resident
                acc0[r] += xa.x * w.x + xa.y * w.y + xa.z * w.z + xa.w * w.w;
                acc1[r] += xb.x * w.x + xb.y * w.y + xb.z * w.z + xb.w * w.w;
            }
        }

        #pragma unroll
        for (int r = 0; r < 8; ++r) {
            float v0 = acc0[r], v1 = acc1[r];
            #pragma unroll
            for (int off = 32; off > 0; off >>= 1) {
                v0 += __shfl_down(v0, off, 64);
                v1 += __shfl_down(v1, off, 64);
            }
            if (lane == 0) {
                ((float*)interm4)[(2 * wave + 0) * 8 + r] = v0 * 4.0f;  // SCALING
                ((float*)interm4)[(2 * wave + 1) * 8 + r] = v1 * 4.0f;
            }
        }
    }
    __syncthreads();

    // ---- Phase 2: out[row0+m][o] = sum_r interm[m][r] * wBt[r][o] ----
    const float4* __restrict__ wt = (const float4*)wBt;      // [8][1024]
    #pragma unroll
    for (int k = 0; k < 4; ++k) {
        const int og = t + 256 * k;                          // float4 col group
        float4 w[8];
        #pragma unroll
        for (int r = 0; r < 8; ++r) w[r] = wt[r * 1024 + og]; // coalesced, L2-hit

        #pragma unroll
        for (int m = 0; m < ROWS; ++m) {
            const float4 i0 = interm4[m][0];
            const float4 i1 = interm4[m][1];
            float4 s;
            s.x = i0.x * w[0].x + i0.y * w[1].x + i0.z * w[2].x + i0.w * w[3].x
                + i1.x * w[4].x + i1.y * w[5].x + i1.z * w[6].x + i1.w * w[7].x;
            s.y = i0.x * w[0].y + i0.y * w[1].y + i0.z * w[2].y + i0.w * w[3].y
                + i1.x * w[4].y + i1.y * w[5].y + i1.z * w[6].y + i1.w * w[7].y;
            s.z = i0.x * w[0].z + i0.y * w[1].z + i0.z * w[2].z + i0.w * w[3].z
                + i1.x * w[4].z + i1.y * w[5].z + i1.z * w[6].z + i1.w * w[7].z;
            s.w = i0.x * w[0].w + i0.y * w[1].w + i0.z * w[2].w + i0.w * w[3].w
                + i1.x * w[4].w + i1.y * w[5].w + i1.z * w[6].w + i1.w * w[7].w;
            ((float4*)(out + (size_t)(row0 + m) * 4096))[og] = s;   // coalesced
        }
    }
}

extern "C" void kernel_launch(void* const* d_in, const int* in_sizes, int n_in,
                              void* d_out, int out_size, void* d_ws, size_t ws_size,
                              hipStream_t stream) {
    const float* x        = (const float*)d_in[0];
    const int*   codes_A  = (const int*)d_in[1];
    const float* absmax_A = (const float*)d_in[2];
    const int*   codes_B  = (const int*)d_in[3];
    const float* absmax_B = (const float*)d_in[4];
    float* out = (float*)d_out;

    constexpr int NW = 8 * 4096;
    float* wA  = (float*)d_ws;            // 128 KB
    float* wBt = (float*)d_ws + NW;       // 128 KB (transposed)

    nf4_dequant_kernel<<<(NW + 255) / 256, 256, 0, stream>>>(
        codes_A, absmax_A, codes_B, absmax_B, wA, wBt, NW);

    qlora_fused_kernel<<<8192 / 8, 256, 0, stream>>>(x, wA, wBt, out);
}